// Round 2
// baseline (433.268 us; speedup 1.0000x reference)
//
#include <hip/hip_runtime.h>

// FaFMIMONet fused warp+aggregate kernel.
// B=4, A=5, C=64, H=W=128.
// out[(i*B+b), c, y, x] = feats[b,i,c,y,x] + sum_j valid(b,i,j) * stage2(stage1(feats[b,j]))
// stage1: rotation-only affine bilinear sample; stage2: constant-translation bilinear sample.
// Both stages fused: per pixel, 8 (row-offset, weightA, weightB) taps shared across channels.

constexpr int Bc = 4, Ac = 5, Cc = 64, Hc = 128, Wc = 128;
constexpr int HWc = Hc * Wc;
constexpr int CHK = 16;   // channel chunk per accumulator pass

__global__ __launch_bounds__(256)
void fafmimo_fuse(const float* __restrict__ feats,
                  const float* __restrict__ trans,
                  const int*   __restrict__ num_agent,
                  float*       __restrict__ out)
{
    const int bi = blockIdx.z;          // 0..B*A-1
    const int b  = bi / Ac;
    const int i  = bi - b * Ac;
    const int x  = (int)(blockIdx.x * 64 + threadIdx.x);   // block (64,4)
    const int y  = (int)(blockIdx.y * 4  + threadIdx.y);
    const int pix = y * Wc + x;

    const int na = num_agent[b * Ac];   // num_agent_tensor[b, 0]

    const float xv = (2.0f * (float)x + 1.0f) / 128.0f - 1.0f;
    const float yv = (2.0f * (float)y + 1.0f) / 128.0f - 1.0f;

    const float* __restrict__ fi = feats + (size_t)(b * Ac + i) * Cc * HWc;
    float* __restrict__ ob = out + (size_t)(i * Bc + b) * Cc * HWc;

    for (int c0 = 0; c0 < Cc; c0 += CHK) {
        float acc[CHK];
        #pragma unroll
        for (int k = 0; k < CHK; ++k) acc[k] = fi[(c0 + k) * HWc + pix];

        if (i < na) {
            for (int j = 0; j < Ac; ++j) {
                if (j == i || j >= na) continue;

                const float* Tm = trans + (size_t)((b * Ac + i) * Ac + j) * 16;
                const float r00 = Tm[0], r01 = Tm[1], t03 = Tm[3];
                const float r10 = Tm[4], r11 = Tm[5], t13 = Tm[7];
                const float x_t =  (4.0f * t03) / 128.0f;
                const float y_t = -(4.0f * t13) / 128.0f;

                // ---- stage 2 (translation-only) sample coords at output pixel ----
                const float ix2 = ((xv + x_t + 1.0f) * 128.0f - 1.0f) * 0.5f;
                const float iy2 = ((yv + y_t + 1.0f) * 128.0f - 1.0f) * 0.5f;
                const float fx0 = floorf(ix2), fy0 = floorf(iy2);
                const float wx1 = ix2 - fx0,   wy1 = iy2 - fy0;
                const float wx0 = 1.0f - wx1,  wy0 = 1.0f - wy1;

                // 8 taps: 4 stage-2 corners x 2 stage-1 rows; each tap covers an x-pair.
                int   off[8];
                float wA[8], wB[8];
                #pragma unroll
                for (int cy = 0; cy < 2; ++cy) {
                    #pragma unroll
                    for (int cx = 0; cx < 2; ++cx) {
                        const float jyf = fy0 + (float)cy;
                        const float jxf = fx0 + (float)cx;
                        const bool v2 = (jyf >= 0.0f) & (jyf <= 127.0f)
                                      & (jxf >= 0.0f) & (jxf <= 127.0f);
                        const float w2 = (cy ? wy1 : wy0) * (cx ? wx1 : wx0)
                                       * (v2 ? 1.0f : 0.0f);
                        const int jy = min(max((int)jyf, 0), 127);
                        const int jx = min(max((int)jxf, 0), 127);

                        // ---- stage 1 (rotation) bilinear at integer pixel (jy,jx) ----
                        const float Xs = (2.0f * (float)jx + 1.0f) / 128.0f - 1.0f;
                        const float Ys = (2.0f * (float)jy + 1.0f) / 128.0f - 1.0f;
                        const float gx = Xs * r00 + Ys * r01;
                        const float gy = Xs * r10 + Ys * r11;
                        const float ixs = ((gx + 1.0f) * 128.0f - 1.0f) * 0.5f;
                        const float iys = ((gy + 1.0f) * 128.0f - 1.0f) * 0.5f;
                        const float sx0 = floorf(ixs), sy0 = floorf(iys);
                        const float u1 = ixs - sx0, v1 = iys - sy0;
                        const float u0 = 1.0f - u1,  v0f = 1.0f - v1;

                        // x-pair handling: load plane[row, xb] and plane[row, xb+1]
                        // with weights a,b; folds border validity/clamping.
                        const bool xin = (sx0 >= 0.0f) & (sx0 <= 126.0f);
                        const float a  = xin ? u0 : ((sx0 == -1.0f)  ? u1 : 0.0f);
                        const float bb = xin ? u1 : ((sx0 == 127.0f) ? u0 : 0.0f);
                        const int xb = min(max((int)sx0, 0), 126);

                        const int e = (cy * 2 + cx) * 2;
                        #pragma unroll
                        for (int r = 0; r < 2; ++r) {
                            const float syr = sy0 + (float)r;
                            const bool vy = (syr >= 0.0f) & (syr <= 127.0f);
                            const float wyr = (r ? v1 : v0f) * (vy ? 1.0f : 0.0f) * w2;
                            const int syc = min(max((int)syr, 0), 127);
                            off[e + r] = syc * Wc + xb;
                            wA[e + r]  = wyr * a;
                            wB[e + r]  = wyr * bb;
                        }
                    }
                }

                const float* __restrict__ fj =
                    feats + (size_t)(b * Ac + j) * Cc * HWc + (size_t)c0 * HWc;
                #pragma unroll 4
                for (int k = 0; k < CHK; ++k) {
                    const float* __restrict__ p = fj + (size_t)k * HWc;
                    float s0 = 0.0f, s1 = 0.0f;
                    #pragma unroll
                    for (int r = 0; r < 8; ++r) {
                        s0 = fmaf(wA[r], p[off[r]],     s0);
                        s1 = fmaf(wB[r], p[off[r] + 1], s1);
                    }
                    acc[k] += s0 + s1;
                }
            }
        }

        #pragma unroll
        for (int k = 0; k < CHK; ++k) ob[(c0 + k) * HWc + pix] = acc[k];
    }
}

extern "C" void kernel_launch(void* const* d_in, const int* in_sizes, int n_in,
                              void* d_out, int out_size, void* d_ws, size_t ws_size,
                              hipStream_t stream) {
    const float* feats     = (const float*)d_in[0];
    const float* trans     = (const float*)d_in[1];
    const int*   num_agent = (const int*)d_in[2];
    float* out = (float*)d_out;

    dim3 grid(Wc / 64, Hc / 4, Bc * Ac);   // (2, 32, 20)
    dim3 block(64, 4, 1);
    hipLaunchKernelGGL(fafmimo_fuse, grid, block, 0, stream,
                       feats, trans, num_agent, out);
}

// Round 3
// 398.673 us; speedup vs baseline: 1.0868x; 1.0868x over previous
//
#include <hip/hip_runtime.h>

// FaFMIMONet fused warp+aggregate kernel. B=4, A=5, C=64, H=W=128.
// out[(i*B+b), c, y, x] = feats[b,i,c,y,x] + sum_j valid(b,i,j) * stage2(stage1(feats[b,j]))
// R3: channel-split across blockIdx.z (4 chunks of 16) -> 5120 blocks for
// occupancy + tail balance; non-temporal output stores.

constexpr int Bc = 4, Ac = 5, Cc = 64, Hc = 128, Wc = 128;
constexpr int HWc = Hc * Wc;
constexpr int CHK = 16;   // channels per block

__global__ __launch_bounds__(256)
void fafmimo_fuse(const float* __restrict__ feats,
                  const float* __restrict__ trans,
                  const int*   __restrict__ num_agent,
                  float*       __restrict__ out)
{
    const int z  = (int)blockIdx.z;          // 0..B*A*(C/CHK)-1
    const int bi = z % (Bc * Ac);
    const int c0 = (z / (Bc * Ac)) * CHK;
    const int b  = bi / Ac;
    const int i  = bi - b * Ac;
    const int x  = (int)(blockIdx.x * 64 + threadIdx.x);   // block (64,4)
    const int y  = (int)(blockIdx.y * 4  + threadIdx.y);
    const int pix = y * Wc + x;

    const int na = num_agent[b * Ac];   // num_agent_tensor[b, 0]

    const float xv = (2.0f * (float)x + 1.0f) / 128.0f - 1.0f;
    const float yv = (2.0f * (float)y + 1.0f) / 128.0f - 1.0f;

    const float* __restrict__ fi =
        feats + (size_t)(b * Ac + i) * Cc * HWc + (size_t)c0 * HWc;
    float* __restrict__ ob =
        out + (size_t)(i * Bc + b) * Cc * HWc + (size_t)c0 * HWc;

    float acc[CHK];
    #pragma unroll
    for (int k = 0; k < CHK; ++k) acc[k] = fi[k * HWc + pix];

    if (i < na) {
        for (int j = 0; j < Ac; ++j) {
            if (j == i || j >= na) continue;

            const float* Tm = trans + (size_t)((b * Ac + i) * Ac + j) * 16;
            const float r00 = Tm[0], r01 = Tm[1], t03 = Tm[3];
            const float r10 = Tm[4], r11 = Tm[5], t13 = Tm[7];
            const float x_t =  (4.0f * t03) / 128.0f;
            const float y_t = -(4.0f * t13) / 128.0f;

            // ---- stage 2 (translation-only) sample coords at output pixel ----
            const float ix2 = ((xv + x_t + 1.0f) * 128.0f - 1.0f) * 0.5f;
            const float iy2 = ((yv + y_t + 1.0f) * 128.0f - 1.0f) * 0.5f;
            const float fx0 = floorf(ix2), fy0 = floorf(iy2);
            const float wx1 = ix2 - fx0,   wy1 = iy2 - fy0;
            const float wx0 = 1.0f - wx1,  wy0 = 1.0f - wy1;

            // 8 taps: 4 stage-2 corners x 2 stage-1 rows; each tap covers an x-pair.
            int   off[8];
            float wA[8], wB[8];
            #pragma unroll
            for (int cy = 0; cy < 2; ++cy) {
                #pragma unroll
                for (int cx = 0; cx < 2; ++cx) {
                    const float jyf = fy0 + (float)cy;
                    const float jxf = fx0 + (float)cx;
                    const bool v2 = (jyf >= 0.0f) & (jyf <= 127.0f)
                                  & (jxf >= 0.0f) & (jxf <= 127.0f);
                    const float w2 = (cy ? wy1 : wy0) * (cx ? wx1 : wx0)
                                   * (v2 ? 1.0f : 0.0f);
                    const int jy = min(max((int)jyf, 0), 127);
                    const int jx = min(max((int)jxf, 0), 127);

                    // ---- stage 1 (rotation) bilinear at integer pixel (jy,jx) ----
                    const float Xs = (2.0f * (float)jx + 1.0f) / 128.0f - 1.0f;
                    const float Ys = (2.0f * (float)jy + 1.0f) / 128.0f - 1.0f;
                    const float gx = Xs * r00 + Ys * r01;
                    const float gy = Xs * r10 + Ys * r11;
                    const float ixs = ((gx + 1.0f) * 128.0f - 1.0f) * 0.5f;
                    const float iys = ((gy + 1.0f) * 128.0f - 1.0f) * 0.5f;
                    const float sx0 = floorf(ixs), sy0 = floorf(iys);
                    const float u1 = ixs - sx0, v1 = iys - sy0;
                    const float u0 = 1.0f - u1,  v0f = 1.0f - v1;

                    // x-pair: load plane[row, xb] and plane[row, xb+1] with
                    // weights a,bb; folds border validity/clamping.
                    const bool xin = (sx0 >= 0.0f) & (sx0 <= 126.0f);
                    const float a  = xin ? u0 : ((sx0 == -1.0f)  ? u1 : 0.0f);
                    const float bb = xin ? u1 : ((sx0 == 127.0f) ? u0 : 0.0f);
                    const int xb = min(max((int)sx0, 0), 126);

                    const int e = (cy * 2 + cx) * 2;
                    #pragma unroll
                    for (int r = 0; r < 2; ++r) {
                        const float syr = sy0 + (float)r;
                        const bool vy = (syr >= 0.0f) & (syr <= 127.0f);
                        const float wyr = (r ? v1 : v0f) * (vy ? 1.0f : 0.0f) * w2;
                        const int syc = min(max((int)syr, 0), 127);
                        off[e + r] = syc * Wc + xb;
                        wA[e + r]  = wyr * a;
                        wB[e + r]  = wyr * bb;
                    }
                }
            }

            const float* __restrict__ fj =
                feats + (size_t)(b * Ac + j) * Cc * HWc + (size_t)c0 * HWc;
            #pragma unroll 4
            for (int k = 0; k < CHK; ++k) {
                const float* __restrict__ p = fj + (size_t)k * HWc;
                float s0 = 0.0f, s1 = 0.0f;
                #pragma unroll
                for (int r = 0; r < 8; ++r) {
                    s0 = fmaf(wA[r], p[off[r]],     s0);
                    s1 = fmaf(wB[r], p[off[r] + 1], s1);
                }
                acc[k] += s0 + s1;
            }
        }
    }

    #pragma unroll
    for (int k = 0; k < CHK; ++k)
        __builtin_nontemporal_store(acc[k], &ob[k * HWc + pix]);
}

extern "C" void kernel_launch(void* const* d_in, const int* in_sizes, int n_in,
                              void* d_out, int out_size, void* d_ws, size_t ws_size,
                              hipStream_t stream) {
    const float* feats     = (const float*)d_in[0];
    const float* trans     = (const float*)d_in[1];
    const int*   num_agent = (const int*)d_in[2];
    float* out = (float*)d_out;

    dim3 grid(Wc / 64, Hc / 4, Bc * Ac * (Cc / CHK));   // (2, 32, 80)
    dim3 block(64, 4, 1);
    hipLaunchKernelGGL(fafmimo_fuse, grid, block, 0, stream,
                       feats, trans, num_agent, out);
}

// Round 4
// 343.247 us; speedup vs baseline: 1.2623x; 1.1615x over previous
//
#include <hip/hip_runtime.h>

// FaFMIMONet fused warp+aggregate. B=4, A=5, C=64, H=W=128.
// R4: repack feats into channel-group-of-4 interleaved layout in d_ws, so each
// bilinear tap is one dwordx4 serving 4 channels (VMEM instrs /4). Fallback to
// direct-gather kernel if ws_size too small.

constexpr int Bc = 4, Ac = 5, Cc = 64, Hc = 128, Wc = 128;
constexpr int HWc = Hc * Wc;
constexpr int NP  = Bc * Ac;     // 20 feature planesets
constexpr int NG  = Cc / 4;      // 16 channel-groups of 4
constexpr size_t WS_NEED = (size_t)NP * Cc * HWc * sizeof(float);  // 83.9 MB

// ---------- repack: feats[p][c][pix] -> ws[p][g][pix][4] ----------
__global__ __launch_bounds__(256)
void fafmimo_repack(const float* __restrict__ feats, float4* __restrict__ ws)
{
    const int idx = (int)(blockIdx.x * 256 + threadIdx.x);  // 0..NP*NG*HWc-1
    const int pix = idx & (HWc - 1);
    const int t   = idx >> 14;          // HWc = 2^14
    const int g   = t & (NG - 1);
    const int p   = t >> 4;
    const float* s = feats + ((size_t)p * Cc + g * 4) * HWc + pix;
    ws[idx] = make_float4(s[0], s[HWc], s[2 * HWc], s[3 * HWc]);
}

// ---------- tap computation shared by both kernels ----------
__device__ __forceinline__ void compute_taps(
    const float* __restrict__ Tm, float xv, float yv,
    int off[8], float wA[8], float wB[8])
{
    const float r00 = Tm[0], r01 = Tm[1], t03 = Tm[3];
    const float r10 = Tm[4], r11 = Tm[5], t13 = Tm[7];
    const float x_t =  (4.0f * t03) / 128.0f;
    const float y_t = -(4.0f * t13) / 128.0f;

    // stage 2 (translation-only) sample coords at output pixel
    const float ix2 = ((xv + x_t + 1.0f) * 128.0f - 1.0f) * 0.5f;
    const float iy2 = ((yv + y_t + 1.0f) * 128.0f - 1.0f) * 0.5f;
    const float fx0 = floorf(ix2), fy0 = floorf(iy2);
    const float wx1 = ix2 - fx0,   wy1 = iy2 - fy0;
    const float wx0 = 1.0f - wx1,  wy0 = 1.0f - wy1;

    #pragma unroll
    for (int cy = 0; cy < 2; ++cy) {
        #pragma unroll
        for (int cx = 0; cx < 2; ++cx) {
            const float jyf = fy0 + (float)cy;
            const float jxf = fx0 + (float)cx;
            const bool v2 = (jyf >= 0.0f) & (jyf <= 127.0f)
                          & (jxf >= 0.0f) & (jxf <= 127.0f);
            const float w2 = (cy ? wy1 : wy0) * (cx ? wx1 : wx0)
                           * (v2 ? 1.0f : 0.0f);
            const int jy = min(max((int)jyf, 0), 127);
            const int jx = min(max((int)jxf, 0), 127);

            // stage 1 (rotation) bilinear at integer pixel (jy,jx)
            const float Xs = (2.0f * (float)jx + 1.0f) / 128.0f - 1.0f;
            const float Ys = (2.0f * (float)jy + 1.0f) / 128.0f - 1.0f;
            const float gx = Xs * r00 + Ys * r01;
            const float gy = Xs * r10 + Ys * r11;
            const float ixs = ((gx + 1.0f) * 128.0f - 1.0f) * 0.5f;
            const float iys = ((gy + 1.0f) * 128.0f - 1.0f) * 0.5f;
            const float sx0 = floorf(ixs), sy0 = floorf(iys);
            const float u1 = ixs - sx0, v1 = iys - sy0;
            const float u0 = 1.0f - u1,  v0f = 1.0f - v1;

            // x-pair: columns xb, xb+1 with weights a, bb (border folded)
            const bool xin = (sx0 >= 0.0f) & (sx0 <= 126.0f);
            const float a  = xin ? u0 : ((sx0 == -1.0f)  ? u1 : 0.0f);
            const float bb = xin ? u1 : ((sx0 == 127.0f) ? u0 : 0.0f);
            const int xb = min(max((int)sx0, 0), 126);

            const int e = (cy * 2 + cx) * 2;
            #pragma unroll
            for (int r = 0; r < 2; ++r) {
                const float syr = sy0 + (float)r;
                const bool vy = (syr >= 0.0f) & (syr <= 127.0f);
                const float wyr = (r ? v1 : v0f) * (vy ? 1.0f : 0.0f) * w2;
                const int syc = min(max((int)syr, 0), 127);
                off[e + r] = syc * Wc + xb;
                wA[e + r]  = wyr * a;
                wB[e + r]  = wyr * bb;
            }
        }
    }
}

// ---------- main: packed float4 gathers ----------
__global__ __launch_bounds__(128)
void fafmimo_main(const float4* __restrict__ ws,
                  const float* __restrict__ trans,
                  const int*   __restrict__ num_agent,
                  float*       __restrict__ out)
{
    const int z  = (int)blockIdx.z;        // 0..NP*4-1
    const int bi = z % NP;
    const int g0 = (z / NP) * 4;           // 4 channel-groups (16 ch) per block
    const int b  = bi / Ac;
    const int i  = bi - b * Ac;
    const int x  = (int)(blockIdx.x * 64 + threadIdx.x);  // block (64,2)
    const int y  = (int)(blockIdx.y * 2  + threadIdx.y);
    const int pix = y * Wc + x;
    const int na = num_agent[b * Ac];

    const float xv = (2.0f * (float)x + 1.0f) / 128.0f - 1.0f;
    const float yv = (2.0f * (float)y + 1.0f) / 128.0f - 1.0f;

    const float4* __restrict__ wi = ws + (size_t)(bi * NG + g0) * HWc;
    float4 acc[4];
    #pragma unroll
    for (int g = 0; g < 4; ++g) acc[g] = wi[(size_t)g * HWc + pix];

    if (i < na) {
        for (int j = 0; j < Ac; ++j) {
            if (j == i || j >= na) continue;

            int off[8]; float wA[8], wB[8];
            compute_taps(trans + (size_t)((b * Ac + i) * Ac + j) * 16,
                         xv, yv, off, wA, wB);

            const float4* __restrict__ wj =
                ws + (size_t)((b * Ac + j) * NG + g0) * HWc;
            #pragma unroll
            for (int g = 0; g < 4; ++g) {
                const float4* __restrict__ pg = wj + (size_t)g * HWc;
                float4 s = acc[g];
                #pragma unroll
                for (int r = 0; r < 8; ++r) {
                    const float4 va = pg[off[r]];
                    const float4 vb = pg[off[r] + 1];
                    s.x = fmaf(wA[r], va.x, s.x);
                    s.y = fmaf(wA[r], va.y, s.y);
                    s.z = fmaf(wA[r], va.z, s.z);
                    s.w = fmaf(wA[r], va.w, s.w);
                    s.x = fmaf(wB[r], vb.x, s.x);
                    s.y = fmaf(wB[r], vb.y, s.y);
                    s.z = fmaf(wB[r], vb.z, s.z);
                    s.w = fmaf(wB[r], vb.w, s.w);
                }
                acc[g] = s;
            }
        }
    }

    float* __restrict__ ob =
        out + ((size_t)(i * Bc + b) * Cc + g0 * 4) * HWc + pix;
    #pragma unroll
    for (int g = 0; g < 4; ++g) {
        __builtin_nontemporal_store(acc[g].x, ob + (size_t)(4 * g + 0) * HWc);
        __builtin_nontemporal_store(acc[g].y, ob + (size_t)(4 * g + 1) * HWc);
        __builtin_nontemporal_store(acc[g].z, ob + (size_t)(4 * g + 2) * HWc);
        __builtin_nontemporal_store(acc[g].w, ob + (size_t)(4 * g + 3) * HWc);
    }
}

// ---------- fallback: direct scalar gathers (R3 kernel) ----------
constexpr int CHK = 16;
__global__ __launch_bounds__(256)
void fafmimo_direct(const float* __restrict__ feats,
                    const float* __restrict__ trans,
                    const int*   __restrict__ num_agent,
                    float*       __restrict__ out)
{
    const int z  = (int)blockIdx.z;
    const int bi = z % NP;
    const int c0 = (z / NP) * CHK;
    const int b  = bi / Ac;
    const int i  = bi - b * Ac;
    const int x  = (int)(blockIdx.x * 64 + threadIdx.x);
    const int y  = (int)(blockIdx.y * 4  + threadIdx.y);
    const int pix = y * Wc + x;
    const int na = num_agent[b * Ac];

    const float xv = (2.0f * (float)x + 1.0f) / 128.0f - 1.0f;
    const float yv = (2.0f * (float)y + 1.0f) / 128.0f - 1.0f;

    const float* __restrict__ fi =
        feats + (size_t)(b * Ac + i) * Cc * HWc + (size_t)c0 * HWc;
    float* __restrict__ ob =
        out + (size_t)(i * Bc + b) * Cc * HWc + (size_t)c0 * HWc;

    float acc[CHK];
    #pragma unroll
    for (int k = 0; k < CHK; ++k) acc[k] = fi[k * HWc + pix];

    if (i < na) {
        for (int j = 0; j < Ac; ++j) {
            if (j == i || j >= na) continue;
            int off[8]; float wA[8], wB[8];
            compute_taps(trans + (size_t)((b * Ac + i) * Ac + j) * 16,
                         xv, yv, off, wA, wB);
            const float* __restrict__ fj =
                feats + (size_t)(b * Ac + j) * Cc * HWc + (size_t)c0 * HWc;
            #pragma unroll 4
            for (int k = 0; k < CHK; ++k) {
                const float* __restrict__ p = fj + (size_t)k * HWc;
                float s0 = 0.0f, s1 = 0.0f;
                #pragma unroll
                for (int r = 0; r < 8; ++r) {
                    s0 = fmaf(wA[r], p[off[r]],     s0);
                    s1 = fmaf(wB[r], p[off[r] + 1], s1);
                }
                acc[k] += s0 + s1;
            }
        }
    }

    #pragma unroll
    for (int k = 0; k < CHK; ++k)
        __builtin_nontemporal_store(acc[k], &ob[k * HWc + pix]);
}

extern "C" void kernel_launch(void* const* d_in, const int* in_sizes, int n_in,
                              void* d_out, int out_size, void* d_ws, size_t ws_size,
                              hipStream_t stream) {
    const float* feats     = (const float*)d_in[0];
    const float* trans     = (const float*)d_in[1];
    const int*   num_agent = (const int*)d_in[2];
    float* out = (float*)d_out;

    if (ws_size >= WS_NEED) {
        float4* ws = (float4*)d_ws;
        hipLaunchKernelGGL(fafmimo_repack, dim3(NP * NG * HWc / 256), dim3(256),
                           0, stream, feats, ws);
        dim3 grid(Wc / 64, Hc / 2, NP * 4);     // (2, 64, 80)
        dim3 block(64, 2, 1);
        hipLaunchKernelGGL(fafmimo_main, grid, block, 0, stream,
                           ws, trans, num_agent, out);
    } else {
        dim3 grid(Wc / 64, Hc / 4, NP * 4);     // (2, 32, 80)
        dim3 block(64, 4, 1);
        hipLaunchKernelGGL(fafmimo_direct, grid, block, 0, stream,
                           feats, trans, num_agent, out);
    }
}

// Round 5
// 211.087 us; speedup vs baseline: 2.0526x; 1.6261x over previous
//
#include <hip/hip_runtime.h>

// FaFMIMONet fused warp+aggregate. B=4, A=5, C=64, H=W=128.
// R5: stage-2 is a constant integer-shift 2x2 stencil (ix2 = x + 2*T03,
// iy2 = y - 2*T13), so per block we compute the stage-1 (rotated) samples on a
// (TH+1)x(TW+1) window ONCE into LDS (4 packed float4 gathers each), then each
// pixel does a 4-tap LDS stencil. Gathers per (pair,group,pixel): 16 -> ~5.1.
// Repack pass now float4-in/float4-out (register transpose).

constexpr int Bc = 4, Ac = 5, Cc = 64, Hc = 128, Wc = 128;
constexpr int HWc = Hc * Wc;
constexpr int NP  = Bc * Ac;      // 20 planesets
constexpr int NG  = Cc / 4;       // 16 channel-groups of 4
constexpr int TW = 64, TH = 4;    // output tile per block
constexpr int WW = TW + 1, WH = TH + 1, WSZ = WW * WH;   // 65*5 = 325
constexpr size_t WS_NEED = (size_t)NP * Cc * HWc * sizeof(float);  // 83.9 MB

// ---------- repack: feats[p][c][pix] -> ws[p][g][pix][4], vectorized ----------
__global__ __launch_bounds__(256)
void fafmimo_repack(const float* __restrict__ feats, float4* __restrict__ ws)
{
    const int idx  = (int)(blockIdx.x * 256 + threadIdx.x); // [0, NP*NG*HWc/4)
    const int pix4 = (idx & 4095) * 4;                      // HWc/4 = 4096
    const int t    = idx >> 12;
    const int g    = t & 15;
    const int p    = t >> 4;
    const float* s = feats + ((size_t)p * Cc + g * 4) * HWc + pix4;
    const float4 r0 = *(const float4*)(s);
    const float4 r1 = *(const float4*)(s + HWc);
    const float4 r2 = *(const float4*)(s + 2 * HWc);
    const float4 r3 = *(const float4*)(s + 3 * HWc);
    float4* d = ws + ((size_t)p * NG + g) * HWc + pix4;
    d[0] = make_float4(r0.x, r1.x, r2.x, r3.x);
    d[1] = make_float4(r0.y, r1.y, r2.y, r3.y);
    d[2] = make_float4(r0.z, r1.z, r2.z, r3.z);
    d[3] = make_float4(r0.w, r1.w, r2.w, r3.w);
}

// ---------- main: LDS w1-window + constant-shift stencil ----------
__global__ __launch_bounds__(256)
void fafmimo_main(const float4* __restrict__ ws,
                  const float* __restrict__ trans,
                  const int*   __restrict__ num_agent,
                  float*       __restrict__ out)
{
    __shared__ float4 w1s[WSZ];

    const int z  = (int)blockIdx.z;        // [0, NP*NG)
    const int bi = z % NP;
    const int g  = z / NP;
    const int b  = bi / Ac;
    const int i  = bi - b * Ac;
    const int tx = (int)threadIdx.x, ty = (int)threadIdx.y;
    const int tid = ty * TW + tx;
    const int x0 = (int)blockIdx.x * TW, y0 = (int)blockIdx.y * TH;
    const int x  = x0 + tx, y = y0 + ty;
    const int pix = y * Wc + x;
    const int na = num_agent[b * Ac];

    const float xv  = (2.0f * (float)x  + 1.0f) / 128.0f - 1.0f;
    const float yv  = (2.0f * (float)y  + 1.0f) / 128.0f - 1.0f;
    const float xv0 = (2.0f * (float)x0 + 1.0f) / 128.0f - 1.0f;
    const float yv0 = (2.0f * (float)y0 + 1.0f) / 128.0f - 1.0f;

    float4 acc = ws[((size_t)bi * NG + g) * HWc + pix];

    if (i < na) {
        for (int j = 0; j < Ac; ++j) {
            if (j == i || j >= na) continue;

            const float* Tm = trans + (size_t)((b * Ac + i) * Ac + j) * 16;
            const float r00 = Tm[0], r01 = Tm[1], t03 = Tm[3];
            const float r10 = Tm[4], r11 = Tm[5], t13 = Tm[7];
            const float x_t =  (4.0f * t03) / 128.0f;
            const float y_t = -(4.0f * t13) / 128.0f;

            // tile-uniform integer shift of the stage-2 corner lattice
            const int fdx = (int)floorf(((xv0 + x_t + 1.0f) * 128.0f - 1.0f) * 0.5f) - x0;
            const int fdy = (int)floorf(((yv0 + y_t + 1.0f) * 128.0f - 1.0f) * 0.5f) - y0;

            const float4* __restrict__ pj =
                ws + ((size_t)((b * Ac + j) * NG) + g) * HWc;

            // ---- cooperative window fill: w1 at integer pixels ----
            for (int e = tid; e < WSZ; e += TW * TH) {
                const int ry = e / WW, rx = e - ry * WW;
                const int jy = y0 + fdy + ry, jx = x0 + fdx + rx;
                const int jyc = min(max(jy, 0), 127);
                const int jxc = min(max(jx, 0), 127);

                const float Xs = (2.0f * (float)jxc + 1.0f) / 128.0f - 1.0f;
                const float Ys = (2.0f * (float)jyc + 1.0f) / 128.0f - 1.0f;
                const float gx = Xs * r00 + Ys * r01;
                const float gy = Xs * r10 + Ys * r11;
                const float ixs = ((gx + 1.0f) * 128.0f - 1.0f) * 0.5f;
                const float iys = ((gy + 1.0f) * 128.0f - 1.0f) * 0.5f;
                const float sx0 = floorf(ixs), sy0 = floorf(iys);
                const float u1 = ixs - sx0, v1 = iys - sy0;
                const float u0 = 1.0f - u1, v0 = 1.0f - v1;

                const bool xin = (sx0 >= 0.0f) & (sx0 <= 126.0f);
                const float a  = xin ? u0 : ((sx0 == -1.0f)  ? u1 : 0.0f);
                const float bb = xin ? u1 : ((sx0 == 127.0f) ? u0 : 0.0f);
                const int xb = min(max((int)sx0, 0), 126);

                const bool vr0 = (sy0 >= 0.0f) & (sy0 <= 127.0f);
                const bool vr1 = (sy0 >= -1.0f) & (sy0 <= 126.0f);
                const float wr0 = v0 * (vr0 ? 1.0f : 0.0f);
                const float wr1 = v1 * (vr1 ? 1.0f : 0.0f);
                const int o0 = min(max((int)sy0, 0), 127) * Wc + xb;
                const int o1 = min(max((int)sy0 + 1, 0), 127) * Wc + xb;

                const float4 t0a = pj[o0], t0b = pj[o0 + 1];
                const float4 t1a = pj[o1], t1b = pj[o1 + 1];
                float4 w1;
                w1.x = wr0 * fmaf(a, t0a.x, bb * t0b.x) + wr1 * fmaf(a, t1a.x, bb * t1b.x);
                w1.y = wr0 * fmaf(a, t0a.y, bb * t0b.y) + wr1 * fmaf(a, t1a.y, bb * t1b.y);
                w1.z = wr0 * fmaf(a, t0a.z, bb * t0b.z) + wr1 * fmaf(a, t1a.z, bb * t1b.z);
                w1.w = wr0 * fmaf(a, t0a.w, bb * t0b.w) + wr1 * fmaf(a, t1a.w, bb * t1b.w);
                w1s[e] = w1;
            }
            __syncthreads();

            // ---- stage-2: 2x2 constant-weight stencil with validity ----
            const float ix2 = ((xv + x_t + 1.0f) * 128.0f - 1.0f) * 0.5f;
            const float iy2 = ((yv + y_t + 1.0f) * 128.0f - 1.0f) * 0.5f;
            const int jx0 = x + fdx, jy0 = y + fdy;
            const float fx1 = ix2 - (float)jx0, fx0 = 1.0f - fx1;
            const float fy1 = iy2 - (float)jy0, fy0 = 1.0f - fy1;
            const float vx0 = (jx0 >= 0 && jx0 <= 127) ? 1.0f : 0.0f;
            const float vx1 = (jx0 >= -1 && jx0 <= 126) ? 1.0f : 0.0f;
            const float vy0 = (jy0 >= 0 && jy0 <= 127) ? 1.0f : 0.0f;
            const float vy1 = (jy0 >= -1 && jy0 <= 126) ? 1.0f : 0.0f;
            const float w00 = fy0 * vy0 * fx0 * vx0;
            const float w01 = fy0 * vy0 * fx1 * vx1;
            const float w10 = fy1 * vy1 * fx0 * vx0;
            const float w11 = fy1 * vy1 * fx1 * vx1;

            const int base = ty * WW + tx;
            const float4 s00 = w1s[base],      s01 = w1s[base + 1];
            const float4 s10 = w1s[base + WW], s11 = w1s[base + WW + 1];
            acc.x += w00 * s00.x + w01 * s01.x + w10 * s10.x + w11 * s11.x;
            acc.y += w00 * s00.y + w01 * s01.y + w10 * s10.y + w11 * s11.y;
            acc.z += w00 * s00.z + w01 * s01.z + w10 * s10.z + w11 * s11.z;
            acc.w += w00 * s00.w + w01 * s01.w + w10 * s10.w + w11 * s11.w;
            __syncthreads();   // LDS reused by next pair
        }
    }

    float* __restrict__ ob =
        out + ((size_t)(i * Bc + b) * Cc + g * 4) * HWc + pix;
    __builtin_nontemporal_store(acc.x, ob);
    __builtin_nontemporal_store(acc.y, ob + HWc);
    __builtin_nontemporal_store(acc.z, ob + 2 * HWc);
    __builtin_nontemporal_store(acc.w, ob + 3 * HWc);
}

// ---------- fallback: direct scalar gathers (R3-style), if ws too small ----------
constexpr int CHK = 16;
__global__ __launch_bounds__(256)
void fafmimo_direct(const float* __restrict__ feats,
                    const float* __restrict__ trans,
                    const int*   __restrict__ num_agent,
                    float*       __restrict__ out)
{
    const int z  = (int)blockIdx.z;
    const int bi = z % NP;
    const int c0 = (z / NP) * CHK;
    const int b  = bi / Ac;
    const int i  = bi - b * Ac;
    const int x  = (int)(blockIdx.x * 64 + threadIdx.x);
    const int y  = (int)(blockIdx.y * 4  + threadIdx.y);
    const int pix = y * Wc + x;
    const int na = num_agent[b * Ac];

    const float xv = (2.0f * (float)x + 1.0f) / 128.0f - 1.0f;
    const float yv = (2.0f * (float)y + 1.0f) / 128.0f - 1.0f;

    const float* __restrict__ fi =
        feats + (size_t)(b * Ac + i) * Cc * HWc + (size_t)c0 * HWc;
    float* __restrict__ ob =
        out + (size_t)(i * Bc + b) * Cc * HWc + (size_t)c0 * HWc;

    float acc[CHK];
    #pragma unroll
    for (int k = 0; k < CHK; ++k) acc[k] = fi[k * HWc + pix];

    if (i < na) {
        for (int j = 0; j < Ac; ++j) {
            if (j == i || j >= na) continue;
            const float* Tm = trans + (size_t)((b * Ac + i) * Ac + j) * 16;
            const float r00 = Tm[0], r01 = Tm[1], t03 = Tm[3];
            const float r10 = Tm[4], r11 = Tm[5], t13 = Tm[7];
            const float x_t =  (4.0f * t03) / 128.0f;
            const float y_t = -(4.0f * t13) / 128.0f;
            const float ix2 = ((xv + x_t + 1.0f) * 128.0f - 1.0f) * 0.5f;
            const float iy2 = ((yv + y_t + 1.0f) * 128.0f - 1.0f) * 0.5f;
            const float fx0 = floorf(ix2), fy0 = floorf(iy2);
            const float wx1 = ix2 - fx0,   wy1 = iy2 - fy0;
            const float wx0 = 1.0f - wx1,  wy0 = 1.0f - wy1;

            int off[8]; float wA[8], wB[8];
            #pragma unroll
            for (int cy = 0; cy < 2; ++cy) {
                #pragma unroll
                for (int cx = 0; cx < 2; ++cx) {
                    const float jyf = fy0 + (float)cy;
                    const float jxf = fx0 + (float)cx;
                    const bool v2 = (jyf >= 0.0f) & (jyf <= 127.0f)
                                  & (jxf >= 0.0f) & (jxf <= 127.0f);
                    const float w2 = (cy ? wy1 : wy0) * (cx ? wx1 : wx0)
                                   * (v2 ? 1.0f : 0.0f);
                    const int jy = min(max((int)jyf, 0), 127);
                    const int jx = min(max((int)jxf, 0), 127);
                    const float Xs = (2.0f * (float)jx + 1.0f) / 128.0f - 1.0f;
                    const float Ys = (2.0f * (float)jy + 1.0f) / 128.0f - 1.0f;
                    const float gx = Xs * r00 + Ys * r01;
                    const float gy = Xs * r10 + Ys * r11;
                    const float ixs = ((gx + 1.0f) * 128.0f - 1.0f) * 0.5f;
                    const float iys = ((gy + 1.0f) * 128.0f - 1.0f) * 0.5f;
                    const float sx0 = floorf(ixs), sy0 = floorf(iys);
                    const float u1 = ixs - sx0, v1 = iys - sy0;
                    const float u0 = 1.0f - u1,  v0f = 1.0f - v1;
                    const bool xin = (sx0 >= 0.0f) & (sx0 <= 126.0f);
                    const float a  = xin ? u0 : ((sx0 == -1.0f)  ? u1 : 0.0f);
                    const float bbp = xin ? u1 : ((sx0 == 127.0f) ? u0 : 0.0f);
                    const int xb = min(max((int)sx0, 0), 126);
                    const int e = (cy * 2 + cx) * 2;
                    #pragma unroll
                    for (int r = 0; r < 2; ++r) {
                        const float syr = sy0 + (float)r;
                        const bool vy = (syr >= 0.0f) & (syr <= 127.0f);
                        const float wyr = (r ? v1 : v0f) * (vy ? 1.0f : 0.0f) * w2;
                        const int syc = min(max((int)syr, 0), 127);
                        off[e + r] = syc * Wc + xb;
                        wA[e + r]  = wyr * a;
                        wB[e + r]  = wyr * bbp;
                    }
                }
            }

            const float* __restrict__ fj =
                feats + (size_t)(b * Ac + j) * Cc * HWc + (size_t)c0 * HWc;
            #pragma unroll 4
            for (int k = 0; k < CHK; ++k) {
                const float* __restrict__ p = fj + (size_t)k * HWc;
                float s0 = 0.0f, s1 = 0.0f;
                #pragma unroll
                for (int r = 0; r < 8; ++r) {
                    s0 = fmaf(wA[r], p[off[r]],     s0);
                    s1 = fmaf(wB[r], p[off[r] + 1], s1);
                }
                acc[k] += s0 + s1;
            }
        }
    }

    #pragma unroll
    for (int k = 0; k < CHK; ++k)
        __builtin_nontemporal_store(acc[k], &ob[k * HWc + pix]);
}

extern "C" void kernel_launch(void* const* d_in, const int* in_sizes, int n_in,
                              void* d_out, int out_size, void* d_ws, size_t ws_size,
                              hipStream_t stream) {
    const float* feats     = (const float*)d_in[0];
    const float* trans     = (const float*)d_in[1];
    const int*   num_agent = (const int*)d_in[2];
    float* out = (float*)d_out;

    if (ws_size >= WS_NEED) {
        float4* ws = (float4*)d_ws;
        hipLaunchKernelGGL(fafmimo_repack, dim3(NP * NG * (HWc / 4) / 256),
                           dim3(256), 0, stream, feats, ws);
        dim3 grid(Wc / TW, Hc / TH, NP * NG);   // (2, 32, 320)
        dim3 block(TW, TH, 1);
        hipLaunchKernelGGL(fafmimo_main, grid, block, 0, stream,
                           ws, trans, num_agent, out);
    } else {
        dim3 grid(Wc / 64, Hc / 4, NP * 4);
        dim3 block(64, 4, 1);
        hipLaunchKernelGGL(fafmimo_direct, grid, block, 0, stream,
                           feats, trans, num_agent, out);
    }
}